// Round 6
// baseline (744.954 us; speedup 1.0000x reference)
//
#include <hip/hip_runtime.h>
#include <math.h>
#include <type_traits>

#define D    2048
#define DC   512
#define DR   64
#define NH   16
#define HD   128
#define Bb   2
#define Tt   2048
#define ROWS (Bb*Tt)   // 4096
#define LDX  2176      // row stride of q_ext / k_ext (2048 + 64 + 64 pad)

typedef __bf16 bf16x8 __attribute__((ext_vector_type(8)));
typedef __bf16 bf16x4 __attribute__((ext_vector_type(4)));
typedef float  f32x4  __attribute__((ext_vector_type(4)));

typedef const void __attribute__((address_space(1))) gvoid;
typedef void       __attribute__((address_space(3))) lvoid;

__device__ __forceinline__ void load_lds16(const void* g, void* l) {
    __builtin_amdgcn_global_load_lds((gvoid*)g, (lvoid*)l, 16, 0, 0);
}

// ============ bf16 MFMA GEMM: C = A[M,K] @ BT[N,K]^T, ldc variants =========
template <bool WF32, bool WBF16>
__global__ __launch_bounds__(256)
void gemm_bt(const __bf16* __restrict__ A, const __bf16* __restrict__ BT,
             float* __restrict__ Cf, __bf16* __restrict__ Cb,
             int M, int K, int ldcf, int ldcb) {
    __shared__ __bf16 As[128 * 32];
    __shared__ __bf16 Bs[128 * 32];

    const int tid  = threadIdx.x;
    const int w    = tid >> 6;
    const int lane = tid & 63;
    const int quad = lane >> 4;
    const int lc   = lane & 15;
    const int bm   = blockIdx.y * 128;
    const int bn   = blockIdx.x * 128;
    const int wm   = (w & 1) * 64;
    const int wn   = (w >> 1) * 64;

    const int sr = w * 32 + (lane >> 2);
    const int sc = (lane & 3) * 8;

    f32x4 acc[4][4] = {};

    for (int k0 = 0; k0 < K; k0 += 32) {
        const __bf16* ga = A  + (size_t)(bm + sr) * K + k0 + sc;
        const __bf16* gb = BT + (size_t)(bn + sr) * K + k0 + sc;
        load_lds16(ga,                  &As[(w * 32) * 32]);
        load_lds16(ga + (size_t)16 * K, &As[(w * 32 + 16) * 32]);
        load_lds16(gb,                  &Bs[(w * 32) * 32]);
        load_lds16(gb + (size_t)16 * K, &Bs[(w * 32 + 16) * 32]);
        __syncthreads();

        bf16x8 af[4], bfr[4];
        #pragma unroll
        for (int mi = 0; mi < 4; ++mi)
            af[mi] = *(bf16x8*)&As[(wm + mi * 16 + lc) * 32 + quad * 8];
        #pragma unroll
        for (int ni = 0; ni < 4; ++ni)
            bfr[ni] = *(bf16x8*)&Bs[(wn + ni * 16 + lc) * 32 + quad * 8];
        #pragma unroll
        for (int mi = 0; mi < 4; ++mi)
            #pragma unroll
            for (int ni = 0; ni < 4; ++ni)
                acc[mi][ni] = __builtin_amdgcn_mfma_f32_16x16x32_bf16(
                    af[mi], bfr[ni], acc[mi][ni], 0, 0, 0);
        __syncthreads();
    }

    #pragma unroll
    for (int mi = 0; mi < 4; ++mi)
        #pragma unroll
        for (int r = 0; r < 4; ++r) {
            const int row = bm + wm + mi * 16 + quad * 4 + r;
            const int col = bn + wn + lc;
            #pragma unroll
            for (int ni = 0; ni < 4; ++ni) {
                float v = acc[mi][ni][r];
                if constexpr (WF32)  Cf[(size_t)row * ldcf + col + ni * 16] = v;
                if constexpr (WBF16) Cb[(size_t)row * ldcb + col + ni * 16] = (__bf16)v;
            }
        }
}

// ============ fp32 -> bf16 convert =========================================
__global__ void f32_to_bf16(const float* __restrict__ in,
                            __bf16* __restrict__ out, int n) {
    int i = blockIdx.x * blockDim.x + threadIdx.x;
    if (i < n) out[i] = (__bf16)in[i];
}

// ============ transpose + convert: W[R][C] f32 -> WT[C][R] bf16 ============
__global__ __launch_bounds__(256)
void transpose_conv(const float* __restrict__ W, __bf16* __restrict__ WT,
                    int R, int C) {
    __shared__ float tile[64][65];
    const int r0 = blockIdx.x * 64;
    const int c0 = blockIdx.y * 64;
    const int tid = threadIdx.x;
    for (int e = tid; e < 64 * 64; e += 256) {
        int i = e >> 6, j = e & 63;
        tile[i][j] = W[(size_t)(r0 + i) * C + c0 + j];
    }
    __syncthreads();
    for (int e = tid; e < 64 * 64; e += 256) {
        int i = e >> 6, j = e & 63;
        WT[(size_t)(c0 + i) * R + r0 + j] = (__bf16)tile[j][i];
    }
}

// ============ RoPE in-place on BOTH ext buffers (cols 2048..2111) ==========
// For the k buffer (sel==1) also writes fp32 roped values into entry 512..575.
__global__ void rope_both(__bf16* __restrict__ qx, __bf16* __restrict__ kx,
                          float* __restrict__ ent) {
    int idx = blockIdx.x * blockDim.x + threadIdx.x;
    if (idx >= 2 * ROWS * 32) return;
    int sel = idx >= ROWS * 32;
    int id2 = idx - sel * ROWS * 32;
    int row = id2 >> 5;
    int i   = id2 & 31;
    int t   = row & (Tt - 1);
    float inv  = powf(10000.0f, -(float)(2 * i) / 64.0f);
    float fr   = (float)t * inv;
    float c = cosf(fr), s = sinf(fr);
    __bf16* v = (sel ? kx : qx) + (size_t)row * LDX + 2048;
    float x1 = (float)v[i], x2 = (float)v[i + 32];
    float o1 = x1 * c - x2 * s;
    float o2 = x2 * c + x1 * s;
    v[i]      = (__bf16)o1;
    v[i + 32] = (__bf16)o2;
    if (sel) {
        ent[(size_t)row * 576 + 512 + i] = o1;
        ent[(size_t)row * 576 + 544 + i] = o2;
    }
}

// ============ V transpose: vb[B][T][D] -> vtb[B][D][T] (bf16) ==============
__global__ __launch_bounds__(256)
void transpose_v(const __bf16* __restrict__ vb, __bf16* __restrict__ vtb) {
    __shared__ __bf16 tile[64][65];
    const int t0 = blockIdx.x * 64;
    const int c0 = blockIdx.y * 64;
    const int b  = blockIdx.z;
    const int tid = threadIdx.x;
    for (int e = tid; e < 64 * 64; e += 256) {
        int i = e >> 6, j = e & 63;
        tile[i][j] = vb[((size_t)(b * Tt + t0 + i)) * D + c0 + j];
    }
    __syncthreads();
    for (int e = tid; e < 64 * 64; e += 256) {
        int i = e >> 6, j = e & 63;
        vtb[((size_t)(b * D + c0 + i)) * Tt + t0 + j] = tile[j][i];
    }
}

// ============ split-KV MFMA flash attention, BQ=128 ========================
// Each block: TWO q-tiles (128 queries) x <=8 KV tiles, sharing K/V staging.
// Separate PsT per q-tile -> the two QK/softmax/PV streams are independent.
#define KS_STR 200
#define VT_STR 72
#define PS_STR 72
#define SPLIT_TILES 8

__device__ __forceinline__ int pbase_qt(int qt) {
    int a = qt >> 3, r = qt & 7;
    return qt + 4 * a * (a - 1) + a * r;
}

__global__ __launch_bounds__(256, 2)
void attn_split(const __bf16* __restrict__ qx, const __bf16* __restrict__ kx,
                const __bf16* __restrict__ vtb, __bf16* __restrict__ opart,
                float* __restrict__ mlpart) {
    const int qp  = 15 - (int)blockIdx.y;      // q-pair, longest-first
    const int qth = 2 * qp + 1;                // upper q-tile index
    const int sp  = blockIdx.x;
    const int t0  = sp * SPLIT_TILES;
    if (t0 > qth) return;
    const int tend = min(t0 + SPLIT_TILES, qth + 1);
    const int hb = blockIdx.z;
    const int h  = hb & (NH - 1);
    const int b  = hb >> 4;
    const int q0 = qp * 128;

    __shared__ __bf16 Ks[64][KS_STR];          // 25.6 KB
    __shared__ __bf16 Vt[128][VT_STR];         // 18.4 KB
    __shared__ __bf16 PsT[2][4][16][PS_STR];   // 18.4 KB (total 62.4 KB)

    const int tid  = threadIdx.x;
    const int w    = tid >> 6;
    const int lane = tid & 63;
    const int quad = lane >> 4;
    const int lc   = lane & 15;

    // ---- Q fragments for both q-tiles (B-operand layout) ----
    bf16x8 aq[2][6];
    #pragma unroll
    for (int qs = 0; qs < 2; ++qs) {
        const __bf16* qrow = qx + (size_t)(b * Tt + q0 + qs * 64 + w * 16 + lc) * LDX;
        #pragma unroll
        for (int kt = 0; kt < 4; ++kt)
            aq[qs][kt] = *(const bf16x8*)(qrow + h * HD + kt * 32 + quad * 8);
        #pragma unroll
        for (int kt = 0; kt < 2; ++kt)
            aq[qs][4 + kt] = *(const bf16x8*)(qrow + 2048 + kt * 32 + quad * 8);
    }

    // ---- staging geometry ----
    int krow[6], kcol[6], kgo[6];
    #pragma unroll
    for (int j = 0; j < 6; ++j) {
        int c   = tid + j * 256;
        int row = c / 24, c24 = c - row * 24;
        krow[j] = row;
        kcol[j] = c24 * 8;
        kgo[j]  = row * LDX + ((c24 < 16) ? (h * HD + c24 * 8)
                                          : (2048 + (c24 - 16) * 8));
    }
    const int vrow = tid >> 3;
    const int vcol = (tid & 7) * 8;
    const __bf16* kb0 = kx + (size_t)b * Tt * LDX;
    const __bf16* vb0 = vtb + ((size_t)b * D + (size_t)h * HD) * Tt;

    bf16x8 pk[6], pvv[4];
    {
        const __bf16* kbt = kb0 + (size_t)(t0 * 64) * LDX;
        const __bf16* vbt = vb0 + t0 * 64;
        #pragma unroll
        for (int j = 0; j < 6; ++j) pk[j] = *(const bf16x8*)(kbt + kgo[j]);
        #pragma unroll
        for (int j = 0; j < 4; ++j)
            pvv[j] = *(const bf16x8*)(vbt + (vrow + j * 32) * Tt + vcol);
    }

    float m_i[2] = {-1e30f, -1e30f}, l_i[2] = {0.f, 0.f};
    f32x4 Of[2][8];
    #pragma unroll
    for (int qs = 0; qs < 2; ++qs)
        #pragma unroll
        for (int n = 0; n < 8; ++n) Of[qs][n] = (f32x4){0.f, 0.f, 0.f, 0.f};

    const float rscale = 0.07216878364870323f;        // 1/sqrt(192)
    const float RL2    = 0.10412413954269697f;        // rscale * log2(e)

    for (int it = t0; it < tend; ++it) {
        const int s0 = it * 64;
        __syncthreads();
        #pragma unroll
        for (int j = 0; j < 6; ++j) *(bf16x8*)&Ks[krow[j]][kcol[j]] = pk[j];
        #pragma unroll
        for (int j = 0; j < 4; ++j) *(bf16x8*)&Vt[vrow + j * 32][vcol] = pvv[j];
        __syncthreads();

        if (it + 1 < tend) {
            const __bf16* kbn = kb0 + (size_t)(s0 + 64) * LDX;
            const __bf16* vbn = vb0 + (s0 + 64);
            #pragma unroll
            for (int j = 0; j < 6; ++j) pk[j] = *(const bf16x8*)(kbn + kgo[j]);
            #pragma unroll
            for (int j = 0; j < 4; ++j)
                pvv[j] = *(const bf16x8*)(vbn + (vrow + j * 32) * Tt + vcol);
        }

        #pragma unroll
        for (int qs = 0; qs < 2; ++qs) {
            const int qglob = q0 + qs * 64 + w * 16 + lc;
            // ---- S^T = K Q^T ----
            f32x4 st[4];
            #pragma unroll
            for (int f = 0; f < 4; ++f) st[f] = (f32x4){0.f, 0.f, 0.f, 0.f};
            #pragma unroll
            for (int kt = 0; kt < 6; ++kt) {
                #pragma unroll
                for (int f = 0; f < 4; ++f) {
                    bf16x8 ak = *(bf16x8*)&Ks[f * 16 + lc][kt * 32 + quad * 8];
                    st[f] = __builtin_amdgcn_mfma_f32_16x16x32_bf16(
                        ak, aq[qs][kt], st[f], 0, 0, 0);
                }
            }

            // ---- softmax over keys (raw-score domain; exp via exp2) ----
            const bool dm = (it >= 2 * qp + qs);
            float mt = -1e30f;
            #pragma unroll
            for (int f = 0; f < 4; ++f)
                #pragma unroll
                for (int r = 0; r < 4; ++r) {
                    float sv = st[f][r];
                    if (dm && (s0 + f * 16 + quad * 4 + r > qglob)) sv = -1e30f;
                    st[f][r] = sv;
                    mt = fmaxf(mt, sv);
                }
            mt = fmaxf(mt, __shfl_xor(mt, 16, 64));
            mt = fmaxf(mt, __shfl_xor(mt, 32, 64));
            float mn  = fmaxf(m_i[qs], mt);
            float al  = __builtin_amdgcn_exp2f((m_i[qs] - mn) * RL2);
            m_i[qs]   = mn;
            float mnl = mn * RL2;
            float rsum = 0.f;
            #pragma unroll
            for (int f = 0; f < 4; ++f) {
                bf16x4 pr;
                #pragma unroll
                for (int r = 0; r < 4; ++r) {
                    float p = __builtin_amdgcn_exp2f(fmaf(st[f][r], RL2, -mnl));
                    pr[r] = (__bf16)p;
                    rsum += p;
                }
                *(bf16x4*)&PsT[qs][w][lc][f * 16 + quad * 4] = pr;
            }
            rsum += __shfl_xor(rsum, 16, 64);
            rsum += __shfl_xor(rsum, 32, 64);
            l_i[qs] = l_i[qs] * al + rsum;
            #pragma unroll
            for (int n = 0; n < 8; ++n)
                #pragma unroll
                for (int r = 0; r < 4; ++r) Of[qs][n][r] *= al;

            // ---- O^T += Vt P^T (wave-private PsT) ----
            #pragma unroll
            for (int kt = 0; kt < 2; ++kt) {
                bf16x8 bp = *(bf16x8*)&PsT[qs][w][lc][kt * 32 + quad * 8];
                #pragma unroll
                for (int n = 0; n < 8; ++n) {
                    bf16x8 av = *(bf16x8*)&Vt[n * 16 + lc][kt * 32 + quad * 8];
                    Of[qs][n] = __builtin_amdgcn_mfma_f32_16x16x32_bf16(
                        av, bp, Of[qs][n], 0, 0, 0);
                }
            }
        }
    }

    // ---- write partials (m in scaled-score domain for the reduce) ----
    #pragma unroll
    for (int qs = 0; qs < 2; ++qs) {
        const int p = hb * 80 + pbase_qt(2 * qp + qs) + sp;
        __bf16* ob = opart + (size_t)p * (64 * 128) + (size_t)(w * 16 + lc) * 128;
        #pragma unroll
        for (int n = 0; n < 8; ++n) {
            bf16x4 o4;
            #pragma unroll
            for (int r = 0; r < 4; ++r) o4[r] = (__bf16)Of[qs][n][r];
            *(bf16x4*)(ob + n * 16 + quad * 4) = o4;
        }
        if (quad == 0) {
            mlpart[(size_t)p * 128 + w * 16 + lc]      = m_i[qs] * rscale;
            mlpart[(size_t)p * 128 + 64 + w * 16 + lc] = l_i[qs];
        }
    }
}

// ============ combine split partials -> aob (bf16) =========================
__global__ __launch_bounds__(256)
void attn_reduce(const __bf16* __restrict__ opart, const float* __restrict__ mlpart,
                 __bf16* __restrict__ aob) {
    const int qt = blockIdx.x;
    const int hb = blockIdx.y;
    const int h  = hb & (NH - 1);
    const int b  = hb >> 4;
    const int nsp = (qt >> 3) + 1;
    const int p0  = hb * 80 + pbase_qt(qt);
    const int tid = threadIdx.x;
    const int ql  = tid >> 2;
    const int cg  = (tid & 3) * 32;

    float M = -1e30f;
    for (int s = 0; s < nsp; ++s)
        M = fmaxf(M, mlpart[(size_t)(p0 + s) * 128 + ql]);
    float L = 0.f;
    float acc[32];
    #pragma unroll
    for (int j = 0; j < 32; ++j) acc[j] = 0.f;
    for (int s = 0; s < nsp; ++s) {
        float ms = mlpart[(size_t)(p0 + s) * 128 + ql];
        float ls = mlpart[(size_t)(p0 + s) * 128 + 64 + ql];
        float sc = __expf(ms - M);
        L += ls * sc;
        const __bf16* op = opart + (size_t)(p0 + s) * (64 * 128) + (size_t)ql * 128 + cg;
        #pragma unroll
        for (int j8 = 0; j8 < 4; ++j8) {
            bf16x8 v = *(const bf16x8*)(op + j8 * 8);
            #pragma unroll
            for (int e = 0; e < 8; ++e) acc[j8 * 8 + e] += sc * (float)v[e];
        }
    }
    float invL = 1.0f / L;
    __bf16* outp = aob + ((size_t)(b * Tt + qt * 64 + ql)) * D + h * HD + cg;
    #pragma unroll
    for (int j8 = 0; j8 < 4; ++j8) {
        bf16x8 v;
        #pragma unroll
        for (int e = 0; e < 8; ++e) v[e] = (__bf16)(acc[j8 * 8 + e] * invL);
        *(bf16x8*)(outp + j8 * 8) = v;
    }
}

extern "C" void kernel_launch(void* const* d_in, const int* in_sizes, int n_in,
                              void* d_out, int out_size, void* d_ws, size_t ws_size,
                              hipStream_t stream) {
    const float* x    = (const float*)d_in[0];
    const float* Wkv  = (const float*)d_in[1];
    const float* Wkup = (const float*)d_in[2];
    const float* Wvup = (const float*)d_in[3];
    const float* Wq   = (const float*)d_in[4];
    const float* Wqr  = (const float*)d_in[5];
    const float* Wkr  = (const float*)d_in[6];
    const float* Wo   = (const float*)d_in[7];

    float* out0 = (float*)d_out;                     // (4096, 2048)
    float* out1 = out0 + (size_t)ROWS * D;           // (4096, 576) entry

    // ---- persistent buffers ----
    char* wsb = (char*)d_ws;
    __bf16* qext = (__bf16*)wsb;  wsb += (size_t)ROWS * LDX * 2;   // 17.8 MB
    __bf16* kext = (__bf16*)wsb;  wsb += (size_t)ROWS * LDX * 2;   // 17.8 MB
    __bf16* vtb  = (__bf16*)wsb;  wsb += (size_t)ROWS * D   * 2;   // 16.8 MB
    __bf16* aob  = (__bf16*)wsb;  wsb += (size_t)ROWS * D   * 2;   // 16.8 MB
    __bf16* WoT  = (__bf16*)wsb;  wsb += (size_t)D * D * 2;        //  8.4 MB

    // ---- phase-1 scratch (dead before attention) / attention partials ----
    char* scratch = wsb;
    __bf16* xb    = (__bf16*)scratch;                        // 16.8 MB
    __bf16* vb    = (__bf16*)(scratch + 16777216);           // 16.8 MB
    __bf16* ckvb  = (__bf16*)(scratch + 33554432);           //  4.2 MB
    __bf16* WkvT  = (__bf16*)(scratch + 37748736);           //  2.1 MB
    __bf16* WqxT  = (__bf16*)(scratch + 39845888);           //  8.9 MB
    __bf16* KupxT = (__bf16*)(scratch + 48758784);           //  2.2 MB
    __bf16* WvupT = (__bf16*)(scratch + 50987008);           //  2.1 MB  (end 53.1 MB)
    // attention-phase aliases (overlay OK: all above dead by then)
    __bf16* opart  = (__bf16*)scratch;                       // 2560 slots * 16KB = 41.9 MB
    float*  mlpart = (float*)(scratch + (size_t)2560 * 64 * 128 * 2);  // 1.3 MB

    dim3 blk(256);

    // --- staging: converts + weight transposes (qr/kr folded in) ---
    f32_to_bf16<<<(ROWS * D + 255) / 256, blk, 0, stream>>>(x, xb, ROWS * D);
    transpose_conv<<<dim3(D / 64, DC / 64), blk, 0, stream>>>(Wkv, WkvT, D, DC);
    transpose_conv<<<dim3(D / 64, D / 64),  blk, 0, stream>>>(Wq, WqxT, D, D);
    transpose_conv<<<dim3(D / 64, 1),       blk, 0, stream>>>(Wqr, WqxT + (size_t)D * D, D, DR);
    transpose_conv<<<dim3(DC / 64, D / 64), blk, 0, stream>>>(Wkup, KupxT, DC, D);
    transpose_conv<<<dim3(DC / 64, 1),      blk, 0, stream>>>(Wkr, KupxT + (size_t)D * DC, DC, DR);
    transpose_conv<<<dim3(DC / 64, D / 64), blk, 0, stream>>>(Wvup, WvupT, DC, D);
    transpose_conv<<<dim3(D / 64, D / 64),  blk, 0, stream>>>(Wo, WoT, D, D);

    // --- ckv = x @ Wkv: fp32 -> entry cols 0..511 (ldc 576), bf16 -> ckvb ---
    gemm_bt<true, true><<<dim3(DC / 128, ROWS / 128), blk, 0, stream>>>(
        xb, WkvT, out1, ckvb, ROWS, D, 576, DC);

    // --- q_ext = x @ [Wq | Wqr]; k_ext = ckv @ [Wkup | Wkr]; rope both ---
    gemm_bt<false, true><<<dim3(LDX / 128, ROWS / 128), blk, 0, stream>>>(
        xb, WqxT, (float*)nullptr, qext, ROWS, D, 0, LDX);
    gemm_bt<false, true><<<dim3(LDX / 128, ROWS / 128), blk, 0, stream>>>(
        ckvb, KupxT, (float*)nullptr, kext, ROWS, DC, 0, LDX);
    rope_both<<<(2 * ROWS * 32 + 255) / 256, blk, 0, stream>>>(qext, kext, out1);

    // --- v = ckv @ Wvup; transpose ---
    gemm_bt<false, true><<<dim3(D / 128, ROWS / 128), blk, 0, stream>>>(
        ckvb, WvupT, (float*)nullptr, vb, ROWS, DC, 0, D);
    transpose_v<<<dim3(Tt / 64, D / 64, Bb), blk, 0, stream>>>(vb, vtb);

    // --- attention: split-KV (BQ=128) + reduce ---
    attn_split<<<dim3(4, Tt / 128, NH * Bb), blk, 0, stream>>>(
        qext, kext, vtb, opart, mlpart);
    attn_reduce<<<dim3(Tt / 64, NH * Bb), blk, 0, stream>>>(opart, mlpart, aob);

    // --- out0 = ao @ Wo ---
    gemm_bt<true, false><<<dim3(D / 128, ROWS / 128), blk, 0, stream>>>(
        aob, WoT, out0, (__bf16*)nullptr, ROWS, D, D, 0);
}